// Round 1
// baseline (3047.763 us; speedup 1.0000x reference)
//
#include <hip/hip_runtime.h>

#define D 64

// ---- degree / normalization ------------------------------------------------

__global__ void fill_ones(float* __restrict__ deg, int n) {
    int i = blockIdx.x * blockDim.x + threadIdx.x;
    if (i < n) deg[i] = 1.0f;  // self-loop contributes 1 to every node
}

__global__ void deg_count(const int* __restrict__ dst, float* __restrict__ deg, int nE) {
    int e = blockIdx.x * blockDim.x + threadIdx.x;
    if (e < nE) atomicAdd(&deg[dst[e]], 1.0f);
}

__global__ void to_rsqrt(float* __restrict__ deg, int n) {
    int i = blockIdx.x * blockDim.x + threadIdx.x;
    if (i < n) deg[i] = rsqrtf(deg[i]);  // deg >= 1 always
}

// ---- aggregation: out = D^-1/2 (A + I) D^-1/2 h ---------------------------

// self-loop term: agg[i] = h[i] * dinv[i]^2   (also serves as the zero-init)
__global__ void self_loop_init(const float* __restrict__ h, const float* __restrict__ dinv,
                               float* __restrict__ agg, int n) {
    int idx = blockIdx.x * blockDim.x + threadIdx.x;
    if (idx < n * D) {
        int row = idx >> 6;
        float di = dinv[row];
        agg[idx] = h[idx] * (di * di);
    }
}

// one edge handled by 16 threads; each thread moves 4 consecutive floats.
// gather read is a coalesced float4; scatter is 4 fp32 global atomics.
__global__ void edge_scatter(const int* __restrict__ src, const int* __restrict__ dst,
                             const float* __restrict__ h, const float* __restrict__ dinv,
                             float* __restrict__ agg, int nE) {
    int t = blockIdx.x * blockDim.x + threadIdx.x;
    int e = t >> 4;
    if (e >= nE) return;
    int part = (t & 15) << 2;
    int s = src[e];
    int d = dst[e];
    float w = dinv[s] * dinv[d];
    float4 v = *reinterpret_cast<const float4*>(h + (size_t)s * D + part);
    float* o = agg + (size_t)d * D + part;
    atomicAdd(o + 0, v.x * w);
    atomicAdd(o + 1, v.y * w);
    atomicAdd(o + 2, v.z * w);
    atomicAdd(o + 3, v.w * w);
}

// ---- 64x64 dense transform: out = act(in @ W [+ bias]) ---------------------
// One wave per row per iteration: lane j owns output feature j.
// W staged in LDS (16 KB); the input row value x[row][k] is broadcast
// across the wave via __shfl from the lane that loaded it.
template <bool RELU, bool BIAS>
__global__ void gemm64(const float* __restrict__ in, const float* __restrict__ W,
                       const float* __restrict__ bias, float* __restrict__ out, int n) {
    __shared__ float Wl[D * D];
    for (int i = threadIdx.x; i < D * D; i += blockDim.x) Wl[i] = W[i];
    __syncthreads();

    int lane = threadIdx.x & 63;
    int wave = threadIdx.x >> 6;
    int wpb  = blockDim.x >> 6;
    float bv = BIAS ? bias[lane] : 0.0f;

    for (int row = blockIdx.x * wpb + wave; row < n; row += gridDim.x * wpb) {
        float a   = in[(size_t)row * D + lane];
        float acc = bv;
#pragma unroll
        for (int k = 0; k < D; ++k) {
            acc = fmaf(__shfl(a, k, 64), Wl[k * D + lane], acc);
        }
        if (RELU) acc = fmaxf(acc, 0.0f);
        out[(size_t)row * D + lane] = acc;
    }
}

// ---- launch ----------------------------------------------------------------

extern "C" void kernel_launch(void* const* d_in, const int* in_sizes, int n_in,
                              void* d_out, int out_size, void* d_ws, size_t ws_size,
                              hipStream_t stream) {
    const float* x  = (const float*)d_in[0];
    const float* W1 = (const float*)d_in[1];
    const float* W2 = (const float*)d_in[2];
    const float* b2 = (const float*)d_in[3];
    const int*   ei = (const int*)d_in[4];

    int n  = in_sizes[0] / D;   // 100000
    int nE = in_sizes[4] / 2;   // 1600000
    const int* src = ei;        // edge_index[0] = message source
    const int* dst = ei + nE;   // edge_index[1] = aggregation target

    // workspace layout: dinv [n] | bufA [n*D] | bufB [n*D]  (~51.6 MB)
    char* ws = (char*)d_ws;
    float* dinv = (float*)ws;
    size_t off = (((size_t)n * sizeof(float)) + 255) & ~(size_t)255;
    float* bufA = (float*)(ws + off);
    off += (((size_t)n * D * sizeof(float)) + 255) & ~(size_t)255;
    float* bufB = (float*)(ws + off);
    float* out = (float*)d_out;

    const int tb = 256;

    // normalization
    fill_ones<<<(n + tb - 1) / tb, tb, 0, stream>>>(dinv, n);
    deg_count<<<(nE + tb - 1) / tb, tb, 0, stream>>>(dst, dinv, nE);
    to_rsqrt<<<(n + tb - 1) / tb, tb, 0, stream>>>(dinv, n);

    int edge_blocks = (int)(((size_t)nE * 16 + tb - 1) / tb);

    // layer 1: bufA = A_hat x ; bufB = relu(bufA @ W1)
    self_loop_init<<<(n * D + tb - 1) / tb, tb, 0, stream>>>(x, dinv, bufA, n);
    edge_scatter<<<edge_blocks, tb, 0, stream>>>(src, dst, x, dinv, bufA, nE);
    gemm64<true, false><<<1024, tb, 0, stream>>>(bufA, W1, nullptr, bufB, n);

    // layer 2: bufA = A_hat bufB ; out = bufA @ W2 + b2
    self_loop_init<<<(n * D + tb - 1) / tb, tb, 0, stream>>>(bufB, dinv, bufA, n);
    edge_scatter<<<edge_blocks, tb, 0, stream>>>(src, dst, bufB, dinv, bufA, nE);
    gemm64<false, true><<<1024, tb, 0, stream>>>(bufA, W2, b2, out, n);
}

// Round 2
// 822.791 us; speedup vs baseline: 3.7042x; 3.7042x over previous
//
#include <hip/hip_runtime.h>

#define D 64

// ---- CSR build -------------------------------------------------------------

__global__ void zero_int(int* __restrict__ p, int n) {
    int i = blockIdx.x * blockDim.x + threadIdx.x;
    if (i < n) p[i] = 0;
}

__global__ void deg_count(const int* __restrict__ dst, int* __restrict__ cnt, int nE) {
    int e = blockIdx.x * blockDim.x + threadIdx.x;
    if (e < nE) atomicAdd(&cnt[dst[e]], 1);
}

// Single-block exclusive scan over counts (in place -> row_ptr), plus cursor
// copy and dinv = rsqrt(deg+1). 1024 threads, each owns a contiguous chunk.
__global__ void scan_build(int* __restrict__ cnt /* n+1: counts in, row_ptr out */,
                           int* __restrict__ cursor, float* __restrict__ dinv, int n) {
    __shared__ int sums[1024];
    int t = threadIdx.x;
    int chunk = (n + 1023) / 1024;
    int lo = min(t * chunk, n);
    int hi = min(lo + chunk, n);
    int s = 0;
    for (int i = lo; i < hi; ++i) s += cnt[i];
    sums[t] = s;
    __syncthreads();
    // Hillis-Steele inclusive scan over the 1024 partial sums
    for (int off = 1; off < 1024; off <<= 1) {
        int v = (t >= off) ? sums[t - off] : 0;
        __syncthreads();
        sums[t] += v;
        __syncthreads();
    }
    int run = (t == 0) ? 0 : sums[t - 1];
    for (int i = lo; i < hi; ++i) {
        int c = cnt[i];
        dinv[i] = rsqrtf(1.0f + (float)c);  // self-loop included
        cnt[i] = run;                        // row_ptr (exclusive)
        cursor[i] = run;
        run += c;
    }
    if (t == 1023) cnt[n] = sums[1023];
}

__global__ void fill_adj(const int* __restrict__ src, const int* __restrict__ dst,
                         int* __restrict__ cursor, int* __restrict__ adj, int nE) {
    int e = blockIdx.x * blockDim.x + threadIdx.x;
    if (e < nE) {
        int pos = atomicAdd(&cursor[dst[e]], 1);
        adj[pos] = src[e];
    }
}

// ---- pre-scale: xp = diag(dinv) * x ---------------------------------------

__global__ void prescale(const float* __restrict__ x, const float* __restrict__ dinv,
                         float* __restrict__ xp, int n) {
    int idx = blockIdx.x * blockDim.x + threadIdx.x;
    if (idx < n * D) xp[idx] = x[idx] * dinv[idx >> 6];
}

// ---- aggregation: S[d] = hp[d] + sum_{s in N(d)} hp[s]  (atomic-free) ------
// One wave per node; lane j owns feature j. Edge list for the node is loaded
// 64-at-a-time into lanes, then broadcast one src at a time via __shfl.
__global__ void aggregate(const float* __restrict__ hp, const int* __restrict__ row_ptr,
                          const int* __restrict__ adj, float* __restrict__ S, int n) {
    int lane = threadIdx.x & 63;
    int wave = (blockIdx.x * blockDim.x + threadIdx.x) >> 6;
    int nw = (gridDim.x * blockDim.x) >> 6;
    for (int node = wave; node < n; node += nw) {
        float acc = hp[(size_t)node * D + lane];  // self-loop term
        int beg = row_ptr[node], end = row_ptr[node + 1];
        for (int base = beg; base < end; base += 64) {
            int cnt = min(64, end - base);
            int s_l = (lane < cnt) ? adj[base + lane] : 0;
            int j = 0;
            for (; j + 4 <= cnt; j += 4) {
                int s0 = __shfl(s_l, j, 64);
                int s1 = __shfl(s_l, j + 1, 64);
                int s2 = __shfl(s_l, j + 2, 64);
                int s3 = __shfl(s_l, j + 3, 64);
                float v0 = hp[(size_t)s0 * D + lane];
                float v1 = hp[(size_t)s1 * D + lane];
                float v2 = hp[(size_t)s2 * D + lane];
                float v3 = hp[(size_t)s3 * D + lane];
                acc += v0; acc += v1; acc += v2; acc += v3;
            }
            for (; j < cnt; ++j) {
                int s = __shfl(s_l, j, 64);
                acc += hp[(size_t)s * D + lane];
            }
        }
        S[(size_t)node * D + lane] = acc;
    }
}

// ---- 64x64 dense transform with folded dinv epilogue -----------------------
// MODE 0: out = dinv[row]^2 * relu(acc)          (layer 1 -> pre-scaled h')
// MODE 1: out = dinv[row] * acc + bias[lane]     (layer 2 -> final output)
template <int MODE>
__global__ void gemm64(const float* __restrict__ in, const float* __restrict__ W,
                       const float* __restrict__ bias, const float* __restrict__ dinv,
                       float* __restrict__ out, int n) {
    __shared__ float Wl[D * D];
    for (int i = threadIdx.x; i < D * D; i += blockDim.x) Wl[i] = W[i];
    __syncthreads();

    int lane = threadIdx.x & 63;
    int wave = threadIdx.x >> 6;
    int wpb  = blockDim.x >> 6;
    float bv = (MODE == 1) ? bias[lane] : 0.0f;

    for (int row = blockIdx.x * wpb + wave; row < n; row += gridDim.x * wpb) {
        float a   = in[(size_t)row * D + lane];
        float acc = 0.0f;
#pragma unroll
        for (int k = 0; k < D; ++k) {
            acc = fmaf(__shfl(a, k, 64), Wl[k * D + lane], acc);
        }
        float di = dinv[row];
        float r;
        if (MODE == 0) r = di * di * fmaxf(acc, 0.0f);
        else           r = di * acc + bv;
        out[(size_t)row * D + lane] = r;
    }
}

// ---- launch ----------------------------------------------------------------

extern "C" void kernel_launch(void* const* d_in, const int* in_sizes, int n_in,
                              void* d_out, int out_size, void* d_ws, size_t ws_size,
                              hipStream_t stream) {
    const float* x  = (const float*)d_in[0];
    const float* W1 = (const float*)d_in[1];
    const float* W2 = (const float*)d_in[2];
    const float* b2 = (const float*)d_in[3];
    const int*   ei = (const int*)d_in[4];

    int n  = in_sizes[0] / D;   // 100000
    int nE = in_sizes[4] / 2;   // 1600000
    const int* src = ei;        // message source
    const int* dst = ei + nE;   // aggregation target

    // workspace layout (aligned to 256B):
    //   row_ptr [n+1] | cursor [n] | dinv [n] | adj [nE] | P [n*D] | Q [n*D]
    auto align = [](size_t v) { return (v + 255) & ~(size_t)255; };
    char* ws = (char*)d_ws;
    size_t off = 0;
    int* row_ptr = (int*)(ws + off);   off += align((size_t)(n + 1) * 4);
    int* cursor  = (int*)(ws + off);   off += align((size_t)n * 4);
    float* dinv  = (float*)(ws + off); off += align((size_t)n * 4);
    int* adj     = (int*)(ws + off);   off += align((size_t)nE * 4);
    float* P     = (float*)(ws + off); off += align((size_t)n * D * 4);
    float* Q     = (float*)(ws + off);
    float* out = (float*)d_out;

    const int tb = 256;
    int eb = (nE + tb - 1) / tb;

    // CSR build
    zero_int<<<(n + 1 + tb - 1) / tb, tb, 0, stream>>>(row_ptr, n + 1);
    deg_count<<<eb, tb, 0, stream>>>(dst, row_ptr, nE);
    scan_build<<<1, 1024, 0, stream>>>(row_ptr, cursor, dinv, n);
    fill_adj<<<eb, tb, 0, stream>>>(src, dst, cursor, adj, nE);

    // layer 1: P = dinv*x ; Q = (A+I)P ; P = dinv^2 * relu(Q @ W1)
    prescale<<<(n * D + tb - 1) / tb, tb, 0, stream>>>(x, dinv, P, n);
    aggregate<<<2048, tb, 0, stream>>>(P, row_ptr, adj, Q, n);
    gemm64<0><<<1024, tb, 0, stream>>>(Q, W1, nullptr, dinv, P, n);

    // layer 2: Q = (A+I)P ; out = dinv * (Q @ W2) + b2
    aggregate<<<2048, tb, 0, stream>>>(P, row_ptr, adj, Q, n);
    gemm64<1><<<1024, tb, 0, stream>>>(Q, W2, b2, dinv, out, n);
}

// Round 3
// 563.897 us; speedup vs baseline: 5.4048x; 1.4591x over previous
//
#include <hip/hip_runtime.h>

#define D 64
#define SCAN_B 1024

// ---- CSR build -------------------------------------------------------------

__global__ void zero_int(int* __restrict__ p, int n) {
    int i = blockIdx.x * blockDim.x + threadIdx.x;
    if (i < n) p[i] = 0;
}

__global__ void deg_count(const int* __restrict__ dst, int* __restrict__ cnt, int nE) {
    int e = blockIdx.x * blockDim.x + threadIdx.x;
    if (e < nE) atomicAdd(&cnt[dst[e]], 1);
}

// Phase 1: per-block sums of 1024-element chunks.
__global__ void block_sums(const int* __restrict__ cnt, int* __restrict__ bsum, int n) {
    __shared__ int red[SCAN_B];
    int idx = blockIdx.x * SCAN_B + threadIdx.x;
    red[threadIdx.x] = (idx < n) ? cnt[idx] : 0;
    __syncthreads();
    for (int off = SCAN_B / 2; off > 0; off >>= 1) {
        if (threadIdx.x < off) red[threadIdx.x] += red[threadIdx.x + off];
        __syncthreads();
    }
    if (threadIdx.x == 0) bsum[blockIdx.x] = red[0];
}

// Phase 2: single block exclusive-scans the (<=1024) block sums; writes total.
__global__ void scan_bsums(int* __restrict__ bsum, int* __restrict__ row_ptr, int nb, int n) {
    __shared__ int s[SCAN_B];
    int t = threadIdx.x;
    int v = (t < nb) ? bsum[t] : 0;
    s[t] = v;
    __syncthreads();
    for (int off = 1; off < SCAN_B; off <<= 1) {
        int u = (t >= off) ? s[t - off] : 0;
        __syncthreads();
        s[t] += u;
        __syncthreads();
    }
    if (t < nb) bsum[t] = s[t] - v;          // exclusive block offsets
    if (t == SCAN_B - 1) row_ptr[n] = s[t];  // grand total (= nE)
}

// Phase 3: in-block exclusive scan + block offset -> row_ptr/cursor/dinv.
// In-place over the counts array is safe: every load happens before the first
// __syncthreads; every store happens after the scan.
__global__ void scan_apply(int* __restrict__ cnt /* counts in, row_ptr out */,
                           const int* __restrict__ bsum, int* __restrict__ cursor,
                           float* __restrict__ dinv, int n) {
    __shared__ int s[SCAN_B];
    int t = threadIdx.x;
    int idx = blockIdx.x * SCAN_B + t;
    int v = (idx < n) ? cnt[idx] : 0;
    s[t] = v;
    __syncthreads();
    for (int off = 1; off < SCAN_B; off <<= 1) {
        int u = (t >= off) ? s[t - off] : 0;
        __syncthreads();
        s[t] += u;
        __syncthreads();
    }
    if (idx < n) {
        int ex = bsum[blockIdx.x] + s[t] - v;  // exclusive prefix
        cnt[idx] = ex;                          // row_ptr
        cursor[idx] = ex;
        dinv[idx] = rsqrtf(1.0f + (float)v);    // self-loop included
    }
}

__global__ void fill_adj(const int* __restrict__ src, const int* __restrict__ dst,
                         int* __restrict__ cursor, int* __restrict__ adj, int nE) {
    int e = blockIdx.x * blockDim.x + threadIdx.x;
    if (e < nE) {
        int pos = atomicAdd(&cursor[dst[e]], 1);
        adj[pos] = src[e];
    }
}

// ---- pre-scale: xp = diag(dinv) * x ---------------------------------------

__global__ void prescale(const float* __restrict__ x, const float* __restrict__ dinv,
                         float* __restrict__ xp, int n) {
    int idx = blockIdx.x * blockDim.x + threadIdx.x;
    if (idx < n * D) xp[idx] = x[idx] * dinv[idx >> 6];
}

// ---- aggregation: S[d] = hp[d] + sum_{s in N(d)} hp[s]  (atomic-free) ------

__global__ void aggregate(const float* __restrict__ hp, const int* __restrict__ row_ptr,
                          const int* __restrict__ adj, float* __restrict__ S, int n) {
    int lane = threadIdx.x & 63;
    int wave = (blockIdx.x * blockDim.x + threadIdx.x) >> 6;
    int nw = (gridDim.x * blockDim.x) >> 6;
    for (int node = wave; node < n; node += nw) {
        float acc = hp[(size_t)node * D + lane];  // self-loop term
        int beg = row_ptr[node], end = row_ptr[node + 1];
        for (int base = beg; base < end; base += 64) {
            int cnt = min(64, end - base);
            int s_l = (lane < cnt) ? adj[base + lane] : 0;
            int j = 0;
            for (; j + 4 <= cnt; j += 4) {
                int s0 = __shfl(s_l, j, 64);
                int s1 = __shfl(s_l, j + 1, 64);
                int s2 = __shfl(s_l, j + 2, 64);
                int s3 = __shfl(s_l, j + 3, 64);
                float v0 = hp[(size_t)s0 * D + lane];
                float v1 = hp[(size_t)s1 * D + lane];
                float v2 = hp[(size_t)s2 * D + lane];
                float v3 = hp[(size_t)s3 * D + lane];
                acc += v0; acc += v1; acc += v2; acc += v3;
            }
            for (; j < cnt; ++j) {
                int s = __shfl(s_l, j, 64);
                acc += hp[(size_t)s * D + lane];
            }
        }
        S[(size_t)node * D + lane] = acc;
    }
}

// ---- 64x64 dense transform with folded dinv epilogue -----------------------
// MODE 0: out = dinv[row]^2 * relu(acc)          (layer 1 -> pre-scaled h')
// MODE 1: out = dinv[row] * acc + bias[lane]     (layer 2 -> final output)
template <int MODE>
__global__ void gemm64(const float* __restrict__ in, const float* __restrict__ W,
                       const float* __restrict__ bias, const float* __restrict__ dinv,
                       float* __restrict__ out, int n) {
    __shared__ float Wl[D * D];
    for (int i = threadIdx.x; i < D * D; i += blockDim.x) Wl[i] = W[i];
    __syncthreads();

    int lane = threadIdx.x & 63;
    int wave = threadIdx.x >> 6;
    int wpb  = blockDim.x >> 6;
    float bv = (MODE == 1) ? bias[lane] : 0.0f;

    for (int row = blockIdx.x * wpb + wave; row < n; row += gridDim.x * wpb) {
        float a   = in[(size_t)row * D + lane];
        float acc = 0.0f;
#pragma unroll
        for (int k = 0; k < D; ++k) {
            acc = fmaf(__shfl(a, k, 64), Wl[k * D + lane], acc);
        }
        float di = dinv[row];
        float r;
        if (MODE == 0) r = di * di * fmaxf(acc, 0.0f);
        else           r = di * acc + bv;
        out[(size_t)row * D + lane] = r;
    }
}

// ---- launch ----------------------------------------------------------------

extern "C" void kernel_launch(void* const* d_in, const int* in_sizes, int n_in,
                              void* d_out, int out_size, void* d_ws, size_t ws_size,
                              hipStream_t stream) {
    const float* x  = (const float*)d_in[0];
    const float* W1 = (const float*)d_in[1];
    const float* W2 = (const float*)d_in[2];
    const float* b2 = (const float*)d_in[3];
    const int*   ei = (const int*)d_in[4];

    int n  = in_sizes[0] / D;   // 100000
    int nE = in_sizes[4] / 2;   // 1600000
    const int* src = ei;        // message source
    const int* dst = ei + nE;   // aggregation target

    // workspace layout (aligned to 256B):
    //   row_ptr [n+1] | cursor [n] | dinv [n] | bsum [1024] | adj [nE] | P | Q
    auto align = [](size_t v) { return (v + 255) & ~(size_t)255; };
    char* ws = (char*)d_ws;
    size_t off = 0;
    int* row_ptr = (int*)(ws + off);   off += align((size_t)(n + 1) * 4);
    int* cursor  = (int*)(ws + off);   off += align((size_t)n * 4);
    float* dinv  = (float*)(ws + off); off += align((size_t)n * 4);
    int* bsum    = (int*)(ws + off);   off += align((size_t)SCAN_B * 4);
    int* adj     = (int*)(ws + off);   off += align((size_t)nE * 4);
    float* P     = (float*)(ws + off); off += align((size_t)n * D * 4);
    float* Q     = (float*)(ws + off);
    float* out = (float*)d_out;

    const int tb = 256;
    int eb = (nE + tb - 1) / tb;
    int nb = (n + SCAN_B - 1) / SCAN_B;  // 98 scan blocks

    // CSR build
    zero_int<<<(n + 1 + tb - 1) / tb, tb, 0, stream>>>(row_ptr, n + 1);
    deg_count<<<eb, tb, 0, stream>>>(dst, row_ptr, nE);
    block_sums<<<nb, SCAN_B, 0, stream>>>(row_ptr, bsum, n);
    scan_bsums<<<1, SCAN_B, 0, stream>>>(bsum, row_ptr, nb, n);
    scan_apply<<<nb, SCAN_B, 0, stream>>>(row_ptr, bsum, cursor, dinv, n);
    fill_adj<<<eb, tb, 0, stream>>>(src, dst, cursor, adj, nE);

    // layer 1: P = dinv*x ; Q = (A+I)P ; P = dinv^2 * relu(Q @ W1)
    prescale<<<(n * D + tb - 1) / tb, tb, 0, stream>>>(x, dinv, P, n);
    aggregate<<<2048, tb, 0, stream>>>(P, row_ptr, adj, Q, n);
    gemm64<0><<<1024, tb, 0, stream>>>(Q, W1, nullptr, dinv, P, n);

    // layer 2: Q = (A+I)P ; out = dinv * (Q @ W2) + b2
    aggregate<<<2048, tb, 0, stream>>>(P, row_ptr, adj, Q, n);
    gemm64<1><<<1024, tb, 0, stream>>>(Q, W2, b2, dinv, out, n);
}

// Round 4
// 539.140 us; speedup vs baseline: 5.6530x; 1.0459x over previous
//
#include <hip/hip_runtime.h>

#define D 64
#define SCAN_B 1024

// ---- CSR build -------------------------------------------------------------

__global__ void zero_int(int* __restrict__ p, int n) {
    int i = blockIdx.x * blockDim.x + threadIdx.x;
    if (i < n) p[i] = 0;
}

__global__ void deg_count(const int* __restrict__ dst, int* __restrict__ cnt, int nE) {
    int e = blockIdx.x * blockDim.x + threadIdx.x;
    if (e < nE) atomicAdd(&cnt[dst[e]], 1);
}

// Phase 1: per-block sums of 1024-element chunks.
__global__ void block_sums(const int* __restrict__ cnt, int* __restrict__ bsum, int n) {
    __shared__ int red[SCAN_B];
    int idx = blockIdx.x * SCAN_B + threadIdx.x;
    red[threadIdx.x] = (idx < n) ? cnt[idx] : 0;
    __syncthreads();
    for (int off = SCAN_B / 2; off > 0; off >>= 1) {
        if (threadIdx.x < off) red[threadIdx.x] += red[threadIdx.x + off];
        __syncthreads();
    }
    if (threadIdx.x == 0) bsum[blockIdx.x] = red[0];
}

// Phase 2: single block exclusive-scans the (<=1024) block sums; writes total.
__global__ void scan_bsums(int* __restrict__ bsum, int* __restrict__ row_ptr, int nb, int n) {
    __shared__ int s[SCAN_B];
    int t = threadIdx.x;
    int v = (t < nb) ? bsum[t] : 0;
    s[t] = v;
    __syncthreads();
    for (int off = 1; off < SCAN_B; off <<= 1) {
        int u = (t >= off) ? s[t - off] : 0;
        __syncthreads();
        s[t] += u;
        __syncthreads();
    }
    if (t < nb) bsum[t] = s[t] - v;          // exclusive block offsets
    if (t == SCAN_B - 1) row_ptr[n] = s[t];  // grand total (= nE)
}

// Phase 3: in-block exclusive scan + block offset -> row_ptr/cursor/dinv.
__global__ void scan_apply(int* __restrict__ cnt /* counts in, row_ptr out */,
                           const int* __restrict__ bsum, int* __restrict__ cursor,
                           float* __restrict__ dinv, int n) {
    __shared__ int s[SCAN_B];
    int t = threadIdx.x;
    int idx = blockIdx.x * SCAN_B + t;
    int v = (idx < n) ? cnt[idx] : 0;
    s[t] = v;
    __syncthreads();
    for (int off = 1; off < SCAN_B; off <<= 1) {
        int u = (t >= off) ? s[t - off] : 0;
        __syncthreads();
        s[t] += u;
        __syncthreads();
    }
    if (idx < n) {
        int ex = bsum[blockIdx.x] + s[t] - v;  // exclusive prefix
        cnt[idx] = ex;                          // row_ptr
        cursor[idx] = ex;
        dinv[idx] = rsqrtf(1.0f + (float)v);    // self-loop included
    }
}

__global__ void fill_adj(const int* __restrict__ src, const int* __restrict__ dst,
                         int* __restrict__ cursor, int* __restrict__ adj, int nE) {
    int e = blockIdx.x * blockDim.x + threadIdx.x;
    if (e < nE) {
        int pos = atomicAdd(&cursor[dst[e]], 1);
        adj[pos] = src[e];
    }
}

// ---- fused layer: out = epi( dinv[i] * ((sum_{s in N(i)+i} dinv[s] h[s]) @ W) )
// One wave per node; lane j owns feature j throughout:
//   gather-accumulate S (lane j holds S[j]) -> shfl-GEMM -> scale/act -> store.
// MODE 0: out = relu(dinv*S@W)        (layer 1, no bias)
// MODE 1: out = dinv*S@W + bias       (layer 2)
template <int MODE>
__global__ void agg_gemm(const float* __restrict__ h, const int* __restrict__ row_ptr,
                         const int* __restrict__ adj, const float* __restrict__ dinv,
                         const float* __restrict__ W, const float* __restrict__ bias,
                         float* __restrict__ out, int n) {
    __shared__ float Wl[D * D];
    for (int i = threadIdx.x; i < D * D; i += blockDim.x) Wl[i] = W[i];
    __syncthreads();

    int lane = threadIdx.x & 63;
    int wave = (blockIdx.x * blockDim.x + threadIdx.x) >> 6;
    int nw = (gridDim.x * blockDim.x) >> 6;
    float bv = (MODE == 1) ? bias[lane] : 0.0f;

    for (int node = wave; node < n; node += nw) {
        float dn = dinv[node];
        float acc = dn * h[(size_t)node * D + lane];  // self-loop term
        int beg = row_ptr[node], end = row_ptr[node + 1];
        for (int base = beg; base < end; base += 64) {
            int cnt = min(64, end - base);
            int idx_l = 0; float dv_l = 0.0f;
            if (lane < cnt) {
                idx_l = adj[base + lane];
                dv_l = dinv[idx_l];
            }
            int j = 0;
            for (; j + 4 <= cnt; j += 4) {
                int   s0 = __shfl(idx_l, j, 64),     s1 = __shfl(idx_l, j + 1, 64);
                int   s2 = __shfl(idx_l, j + 2, 64), s3 = __shfl(idx_l, j + 3, 64);
                float w0 = __shfl(dv_l, j, 64),      w1 = __shfl(dv_l, j + 1, 64);
                float w2 = __shfl(dv_l, j + 2, 64),  w3 = __shfl(dv_l, j + 3, 64);
                float v0 = h[(size_t)s0 * D + lane];
                float v1 = h[(size_t)s1 * D + lane];
                float v2 = h[(size_t)s2 * D + lane];
                float v3 = h[(size_t)s3 * D + lane];
                acc = fmaf(w0, v0, acc);
                acc = fmaf(w1, v1, acc);
                acc = fmaf(w2, v2, acc);
                acc = fmaf(w3, v3, acc);
            }
            for (; j < cnt; ++j) {
                int   s = __shfl(idx_l, j, 64);
                float w = __shfl(dv_l, j, 64);
                acc = fmaf(w, h[(size_t)s * D + lane], acc);
            }
        }
        // dense transform: lane j computes sum_k S[k] * W[k][j]
        float y = 0.0f;
#pragma unroll
        for (int k = 0; k < D; ++k) {
            y = fmaf(__shfl(acc, k, 64), Wl[k * D + lane], y);
        }
        float r;
        if (MODE == 0) r = fmaxf(dn * y, 0.0f);
        else           r = fmaf(dn, y, bv);
        out[(size_t)node * D + lane] = r;
    }
}

// ---- launch ----------------------------------------------------------------

extern "C" void kernel_launch(void* const* d_in, const int* in_sizes, int n_in,
                              void* d_out, int out_size, void* d_ws, size_t ws_size,
                              hipStream_t stream) {
    const float* x  = (const float*)d_in[0];
    const float* W1 = (const float*)d_in[1];
    const float* W2 = (const float*)d_in[2];
    const float* b2 = (const float*)d_in[3];
    const int*   ei = (const int*)d_in[4];

    int n  = in_sizes[0] / D;   // 100000
    int nE = in_sizes[4] / 2;   // 1600000
    const int* src = ei;        // message source
    const int* dst = ei + nE;   // aggregation target

    // workspace layout (aligned to 256B):
    //   row_ptr [n+1] | cursor [n] | dinv [n] | bsum [1024] | adj [nE] | H [n*D]
    auto align = [](size_t v) { return (v + 255) & ~(size_t)255; };
    char* ws = (char*)d_ws;
    size_t off = 0;
    int* row_ptr = (int*)(ws + off);   off += align((size_t)(n + 1) * 4);
    int* cursor  = (int*)(ws + off);   off += align((size_t)n * 4);
    float* dinv  = (float*)(ws + off); off += align((size_t)n * 4);
    int* bsum    = (int*)(ws + off);   off += align((size_t)SCAN_B * 4);
    int* adj     = (int*)(ws + off);   off += align((size_t)nE * 4);
    float* H     = (float*)(ws + off);
    float* out = (float*)d_out;

    const int tb = 256;
    int eb = (nE + tb - 1) / tb;
    int nb = (n + SCAN_B - 1) / SCAN_B;

    // CSR build
    zero_int<<<(n + 1 + tb - 1) / tb, tb, 0, stream>>>(row_ptr, n + 1);
    deg_count<<<eb, tb, 0, stream>>>(dst, row_ptr, nE);
    block_sums<<<nb, SCAN_B, 0, stream>>>(row_ptr, bsum, n);
    scan_bsums<<<1, SCAN_B, 0, stream>>>(bsum, row_ptr, nb, n);
    scan_apply<<<nb, SCAN_B, 0, stream>>>(row_ptr, bsum, cursor, dinv, n);
    fill_adj<<<eb, tb, 0, stream>>>(src, dst, cursor, adj, nE);

    // layer 1 fused: H = relu(dinv * ((A_hat-gather of dinv*x) @ W1))
    agg_gemm<0><<<2048, tb, 0, stream>>>(x, row_ptr, adj, dinv, W1, nullptr, H, n);
    // layer 2 fused: out = dinv * (gather @ W2) + b2
    agg_gemm<1><<<2048, tb, 0, stream>>>(H, row_ptr, adj, dinv, W2, b2, out, n);
}

// Round 5
// 501.291 us; speedup vs baseline: 6.0798x; 1.0755x over previous
//
#include <hip/hip_runtime.h>

#define D 64
#define SCAN_B 1024

// ---- CSR build -------------------------------------------------------------

__global__ void zero_int(int* __restrict__ p, int n) {
    int i = blockIdx.x * blockDim.x + threadIdx.x;
    if (i < n) p[i] = 0;
}

__global__ void deg_count(const int* __restrict__ dst, int* __restrict__ cnt, int nE) {
    int e = blockIdx.x * blockDim.x + threadIdx.x;
    if (e < nE) atomicAdd(&cnt[dst[e]], 1);
}

// Phase 1: per-block sums of 1024-element chunks.
__global__ void block_sums(const int* __restrict__ cnt, int* __restrict__ bsum, int n) {
    __shared__ int red[SCAN_B];
    int idx = blockIdx.x * SCAN_B + threadIdx.x;
    red[threadIdx.x] = (idx < n) ? cnt[idx] : 0;
    __syncthreads();
    for (int off = SCAN_B / 2; off > 0; off >>= 1) {
        if (threadIdx.x < off) red[threadIdx.x] += red[threadIdx.x + off];
        __syncthreads();
    }
    if (threadIdx.x == 0) bsum[blockIdx.x] = red[0];
}

// Phase 2: single block exclusive-scans the (<=1024) block sums; writes total.
__global__ void scan_bsums(int* __restrict__ bsum, int* __restrict__ row_ptr, int nb, int n) {
    __shared__ int s[SCAN_B];
    int t = threadIdx.x;
    int v = (t < nb) ? bsum[t] : 0;
    s[t] = v;
    __syncthreads();
    for (int off = 1; off < SCAN_B; off <<= 1) {
        int u = (t >= off) ? s[t - off] : 0;
        __syncthreads();
        s[t] += u;
        __syncthreads();
    }
    if (t < nb) bsum[t] = s[t] - v;          // exclusive block offsets
    if (t == SCAN_B - 1) row_ptr[n] = s[t];  // grand total (= nE)
}

// Phase 3: in-block exclusive scan + block offset -> row_ptr/cursor/dinv.
__global__ void scan_apply(int* __restrict__ cnt /* counts in, row_ptr out */,
                           const int* __restrict__ bsum, int* __restrict__ cursor,
                           float* __restrict__ dinv, int n) {
    __shared__ int s[SCAN_B];
    int t = threadIdx.x;
    int idx = blockIdx.x * SCAN_B + t;
    int v = (idx < n) ? cnt[idx] : 0;
    s[t] = v;
    __syncthreads();
    for (int off = 1; off < SCAN_B; off <<= 1) {
        int u = (t >= off) ? s[t - off] : 0;
        __syncthreads();
        s[t] += u;
        __syncthreads();
    }
    if (idx < n) {
        int ex = bsum[blockIdx.x] + s[t] - v;  // exclusive prefix
        cnt[idx] = ex;                          // row_ptr
        cursor[idx] = ex;
        dinv[idx] = rsqrtf(1.0f + (float)v);    // self-loop included
    }
}

__global__ void fill_adj(const int* __restrict__ src, const int* __restrict__ dst,
                         int* __restrict__ cursor, int* __restrict__ adj, int nE) {
    int e = blockIdx.x * blockDim.x + threadIdx.x;
    if (e < nE) {
        int pos = atomicAdd(&cursor[dst[e]], 1);
        adj[pos] = src[e];
    }
}

// ---- fused layer: out = epi( dinv[i] * ((sum_{s in N(i)+i} dinv[s] h[s]) @ W) )
// One wave per node, quarter-wave row layout: lane (q=lane>>4, p=lane&15)
// accumulates features [4p..4p+3] (float4) over edges e == q (mod 4). One load
// instruction covers 4 edge-rows (64 lanes x 16 B = 1 KB); unroll x2 keeps 8
// rows in flight. Quarters folded with shfl_xor(16|32), then shfl-GEMM.
// MODE 0: out = relu(dinv*S@W)        (layer 1, no bias)
// MODE 1: out = dinv*S@W + bias       (layer 2)
template <int MODE>
__global__ void agg_gemm(const float* __restrict__ h, const int* __restrict__ row_ptr,
                         const int* __restrict__ adj, const float* __restrict__ dinv,
                         const float* __restrict__ W, const float* __restrict__ bias,
                         float* __restrict__ out, int n) {
    __shared__ float Wl[D * D];
    for (int i = threadIdx.x; i < D * D; i += blockDim.x) Wl[i] = W[i];
    __syncthreads();

    int lane = threadIdx.x & 63;
    int q = lane >> 4;   // quarter 0..3  (edge e mod 4)
    int p = lane & 15;   // feature group: features 4p..4p+3
    int wave = (blockIdx.x * blockDim.x + threadIdx.x) >> 6;
    int nw = (gridDim.x * blockDim.x) >> 6;
    float bv = (MODE == 1) ? bias[lane] : 0.0f;

    for (int node = wave; node < n; node += nw) {
        float dn = dinv[node];
        // self-loop term only in quarter 0 (quarters are summed later)
        float4 sv = reinterpret_cast<const float4*>(h + (size_t)node * D)[p];
        float m = (q == 0) ? dn : 0.0f;
        float4 acc;
        acc.x = m * sv.x; acc.y = m * sv.y; acc.z = m * sv.z; acc.w = m * sv.w;

        int beg = row_ptr[node], end = row_ptr[node + 1];
        for (int base = beg; base < end; base += 64) {
            int cnt = min(64, end - base);
            int   idx_l = 0;
            float dv_l  = 0.0f;
            if (lane < cnt) {
                idx_l = adj[base + lane];
                dv_l  = dinv[idx_l];
            }
            // lanes >= cnt hold (0, 0.0f), so tails need no predication:
            // shfl from them yields weight 0 -> harmless load of row 0.
            for (int j = 0; j < cnt; j += 8) {
                int e0 = j + q, e1 = j + 4 + q;          // e0,e1 < 64 always
                int   s0 = __shfl(idx_l, e0, 64);
                float w0 = __shfl(dv_l,  e0, 64);
                int   s1 = __shfl(idx_l, e1, 64);
                float w1 = __shfl(dv_l,  e1, 64);
                float4 v0 = reinterpret_cast<const float4*>(h + (size_t)s0 * D)[p];
                float4 v1 = reinterpret_cast<const float4*>(h + (size_t)s1 * D)[p];
                acc.x = fmaf(w0, v0.x, acc.x);
                acc.y = fmaf(w0, v0.y, acc.y);
                acc.z = fmaf(w0, v0.z, acc.z);
                acc.w = fmaf(w0, v0.w, acc.w);
                acc.x = fmaf(w1, v1.x, acc.x);
                acc.y = fmaf(w1, v1.y, acc.y);
                acc.z = fmaf(w1, v1.z, acc.z);
                acc.w = fmaf(w1, v1.w, acc.w);
            }
        }
        // fold the 4 quarters: after this every lane with group p holds
        // S[4p..4p+3] (identical across quarters).
        acc.x += __shfl_xor(acc.x, 16, 64);
        acc.y += __shfl_xor(acc.y, 16, 64);
        acc.z += __shfl_xor(acc.z, 16, 64);
        acc.w += __shfl_xor(acc.w, 16, 64);
        acc.x += __shfl_xor(acc.x, 32, 64);
        acc.y += __shfl_xor(acc.y, 32, 64);
        acc.z += __shfl_xor(acc.z, 32, 64);
        acc.w += __shfl_xor(acc.w, 32, 64);

        // dense transform: lane j computes sum_k S[k] * W[k][j]
        float y = 0.0f;
#pragma unroll
        for (int pp = 0; pp < 16; ++pp) {
            float sx = __shfl(acc.x, pp, 64);
            float sy = __shfl(acc.y, pp, 64);
            float sz = __shfl(acc.z, pp, 64);
            float sw = __shfl(acc.w, pp, 64);
            y = fmaf(sx, Wl[(4 * pp + 0) * D + lane], y);
            y = fmaf(sy, Wl[(4 * pp + 1) * D + lane], y);
            y = fmaf(sz, Wl[(4 * pp + 2) * D + lane], y);
            y = fmaf(sw, Wl[(4 * pp + 3) * D + lane], y);
        }
        float r;
        if (MODE == 0) r = fmaxf(dn * y, 0.0f);
        else           r = fmaf(dn, y, bv);
        out[(size_t)node * D + lane] = r;
    }
}

// ---- launch ----------------------------------------------------------------

extern "C" void kernel_launch(void* const* d_in, const int* in_sizes, int n_in,
                              void* d_out, int out_size, void* d_ws, size_t ws_size,
                              hipStream_t stream) {
    const float* x  = (const float*)d_in[0];
    const float* W1 = (const float*)d_in[1];
    const float* W2 = (const float*)d_in[2];
    const float* b2 = (const float*)d_in[3];
    const int*   ei = (const int*)d_in[4];

    int n  = in_sizes[0] / D;   // 100000
    int nE = in_sizes[4] / 2;   // 1600000
    const int* src = ei;        // message source
    const int* dst = ei + nE;   // aggregation target

    // workspace layout (aligned to 256B):
    //   row_ptr [n+1] | cursor [n] | dinv [n] | bsum [1024] | adj [nE] | H [n*D]
    auto align = [](size_t v) { return (v + 255) & ~(size_t)255; };
    char* ws = (char*)d_ws;
    size_t off = 0;
    int* row_ptr = (int*)(ws + off);   off += align((size_t)(n + 1) * 4);
    int* cursor  = (int*)(ws + off);   off += align((size_t)n * 4);
    float* dinv  = (float*)(ws + off); off += align((size_t)n * 4);
    int* bsum    = (int*)(ws + off);   off += align((size_t)SCAN_B * 4);
    int* adj     = (int*)(ws + off);   off += align((size_t)nE * 4);
    float* H     = (float*)(ws + off);
    float* out = (float*)d_out;

    const int tb = 256;
    int eb = (nE + tb - 1) / tb;
    int nb = (n + SCAN_B - 1) / SCAN_B;

    // CSR build
    zero_int<<<(n + 1 + tb - 1) / tb, tb, 0, stream>>>(row_ptr, n + 1);
    deg_count<<<eb, tb, 0, stream>>>(dst, row_ptr, nE);
    block_sums<<<nb, SCAN_B, 0, stream>>>(row_ptr, bsum, n);
    scan_bsums<<<1, SCAN_B, 0, stream>>>(bsum, row_ptr, nb, n);
    scan_apply<<<nb, SCAN_B, 0, stream>>>(row_ptr, bsum, cursor, dinv, n);
    fill_adj<<<eb, tb, 0, stream>>>(src, dst, cursor, adj, nE);

    // layer 1 fused: H = relu(dinv * ((A_hat-gather of dinv*x) @ W1))
    agg_gemm<0><<<2048, tb, 0, stream>>>(x, row_ptr, adj, dinv, W1, nullptr, H, n);
    // layer 2 fused: out = dinv * (gather @ W2) + b2
    agg_gemm<1><<<2048, tb, 0, stream>>>(H, row_ptr, adj, dinv, W2, b2, out, n);
}

// Round 6
// 360.479 us; speedup vs baseline: 8.4548x; 1.3906x over previous
//
#include <hip/hip_runtime.h>

#define D 64
#define CHUNK 8192          // edges per partition block
#define BKT_SHIFT 10        // 1024 nodes per bucket
#define BKT_NODES 1024

// ---- misc ------------------------------------------------------------------

__global__ void zero_int(int* __restrict__ p, int n) {
    int i = blockIdx.x * blockDim.x + threadIdx.x;
    if (i < n) p[i] = 0;
}

// ---- level-1: bucket histogram of dst>>BKT_SHIFT ---------------------------

__global__ void bucket_hist(const int* __restrict__ dst, int* __restrict__ bucket_cnt,
                            int nE) {
    __shared__ int h[128];
    int t = threadIdx.x;
    if (t < 128) h[t] = 0;
    __syncthreads();
    int i0 = blockIdx.x * CHUNK;
    int cn = min(CHUNK, nE - i0);
    for (int i = t; i < cn; i += 256) atomicAdd(&h[dst[i0 + i] >> BKT_SHIFT], 1);
    __syncthreads();
    if (t < 128 && h[t] > 0) atomicAdd(&bucket_cnt[t], h[t]);
}

// ---- scan the <=128 bucket counts -> base & cursor; row_ptr[n] = nE --------

__global__ void scan_buckets(const int* __restrict__ bucket_cnt, int* __restrict__ bucket_base,
                             int* __restrict__ bucket_cursor, int* __restrict__ row_ptr,
                             int B, int n) {
    __shared__ int s[128];
    int t = threadIdx.x;  // 128 threads
    int v = (t < B) ? bucket_cnt[t] : 0;
    s[t] = v;
    __syncthreads();
    for (int off = 1; off < 128; off <<= 1) {
        int u = (t >= off) ? s[t - off] : 0;
        __syncthreads();
        s[t] += u;
        __syncthreads();
    }
    if (t < B) {
        int excl = s[t] - v;
        bucket_base[t] = excl;
        bucket_cursor[t] = excl;
    }
    if (t == 127) {
        bucket_base[B] = s[127];   // == nE
        row_ptr[n] = s[127];
    }
}

// ---- level-1 partition: chunk -> in-LDS counting sort -> contiguous runs ---
// Packed word: (dst & (BKT_NODES-1)) << 17 | src     (src < 2^17)

__global__ void partition(const int* __restrict__ src, const int* __restrict__ dst,
                          int* __restrict__ bucket_cursor, int* __restrict__ packed,
                          int nE, int B) {
    __shared__ int hist[128];            // counts, then local cursor
    __shared__ int delta[128];           // global_base - local_excl
    __shared__ int sorted[CHUNK];
    __shared__ unsigned char sortedb[CHUNK];
    int t = threadIdx.x;  // 256 threads
    int i0 = blockIdx.x * CHUNK;
    int cn = min(CHUNK, nE - i0);

    if (t < 128) hist[t] = 0;
    __syncthreads();
    for (int i = t; i < cn; i += 256) atomicAdd(&hist[dst[i0 + i] >> BKT_SHIFT], 1);
    __syncthreads();

    // exclusive scan of the 128 counts (Hillis-Steele, in place is unsafe ->
    // save count in v, scan a copy)
    __shared__ int s[128];
    int v = (t < 128) ? hist[t] : 0;
    if (t < 128) s[t] = v;
    __syncthreads();
    for (int off = 1; off < 128; off <<= 1) {
        int u = (t >= off && t < 128) ? s[t - off] : 0;
        __syncthreads();
        if (t < 128) s[t] += u;
        __syncthreads();
    }
    if (t < 128) {
        int excl = s[t] - v;
        int rb = 0;
        if (t < B && v > 0) rb = atomicAdd(&bucket_cursor[t], v);
        delta[t] = rb - excl;
        hist[t] = excl;   // local cursor for the LDS scatter
    }
    __syncthreads();

    // scatter chunk into LDS, grouped by bucket
    for (int i = t; i < cn; i += 256) {
        int d = dst[i0 + i];
        int b = d >> BKT_SHIFT;
        int p = atomicAdd(&hist[b], 1);
        sorted[p]  = ((d & (BKT_NODES - 1)) << 17) | src[i0 + i];
        sortedb[p] = (unsigned char)b;
    }
    __syncthreads();

    // contiguous-run copy out: element at LDS slot i goes to delta[b] + i
    for (int i = t; i < cn; i += 256) {
        packed[delta[sortedb[i]] + i] = sorted[i];
    }
}

// ---- level-2: per-bucket CSR finalize (count, scan, scatter in one window) -

__global__ void bucket_csr(const int* __restrict__ packed, const int* __restrict__ bucket_base,
                           int* __restrict__ row_ptr, float* __restrict__ dinv,
                           int* __restrict__ adj, int n) {
    __shared__ int s[BKT_NODES];
    __shared__ int cur[BKT_NODES];
    int t = threadIdx.x;  // 1024 threads
    int b = blockIdx.x;
    int lo = bucket_base[b], hi = bucket_base[b + 1];

    s[t] = 0;
    __syncthreads();
    for (int i = lo + t; i < hi; i += BKT_NODES) atomicAdd(&s[packed[i] >> 17], 1);
    __syncthreads();

    int v = s[t];
    __syncthreads();
    for (int off = 1; off < BKT_NODES; off <<= 1) {
        int u = (t >= off) ? s[t - off] : 0;
        __syncthreads();
        s[t] += u;
        __syncthreads();
    }
    int gbeg = lo + s[t] - v;   // exclusive prefix + bucket base
    int node = (b << BKT_SHIFT) + t;
    if (node < n) {
        row_ptr[node] = gbeg;
        dinv[node] = rsqrtf(1.0f + (float)v);   // self-loop included
    }
    cur[t] = gbeg;
    __syncthreads();

    for (int i = lo + t; i < hi; i += BKT_NODES) {
        int w = packed[i];
        int pos = atomicAdd(&cur[w >> 17], 1);
        adj[pos] = w & 0x1FFFF;
    }
}

// ---- fused layer: out = epi( dinv[i] * ((sum_{s in N(i)+i} dinv[s] h[s]) @ W) )
// One wave per node, quarter-wave row layout: lane (q=lane>>4, p=lane&15)
// accumulates features [4p..4p+3] (float4) over edges e == q (mod 4).
// MODE 0: out = relu(dinv*S@W)        (layer 1, no bias)
// MODE 1: out = dinv*S@W + bias       (layer 2)
template <int MODE>
__global__ void agg_gemm(const float* __restrict__ h, const int* __restrict__ row_ptr,
                         const int* __restrict__ adj, const float* __restrict__ dinv,
                         const float* __restrict__ W, const float* __restrict__ bias,
                         float* __restrict__ out, int n) {
    __shared__ float Wl[D * D];
    for (int i = threadIdx.x; i < D * D; i += blockDim.x) Wl[i] = W[i];
    __syncthreads();

    int lane = threadIdx.x & 63;
    int q = lane >> 4;   // quarter 0..3  (edge e mod 4)
    int p = lane & 15;   // feature group: features 4p..4p+3
    int wave = (blockIdx.x * blockDim.x + threadIdx.x) >> 6;
    int nw = (gridDim.x * blockDim.x) >> 6;
    float bv = (MODE == 1) ? bias[lane] : 0.0f;

    for (int node = wave; node < n; node += nw) {
        float dn = dinv[node];
        float4 sv = reinterpret_cast<const float4*>(h + (size_t)node * D)[p];
        float m = (q == 0) ? dn : 0.0f;
        float4 acc;
        acc.x = m * sv.x; acc.y = m * sv.y; acc.z = m * sv.z; acc.w = m * sv.w;

        int beg = row_ptr[node], end = row_ptr[node + 1];
        for (int base = beg; base < end; base += 64) {
            int cnt = min(64, end - base);
            int   idx_l = 0;
            float dv_l  = 0.0f;
            if (lane < cnt) {
                idx_l = adj[base + lane];
                dv_l  = dinv[idx_l];
            }
            for (int j = 0; j < cnt; j += 8) {
                int e0 = j + q, e1 = j + 4 + q;
                int   s0 = __shfl(idx_l, e0, 64);
                float w0 = __shfl(dv_l,  e0, 64);
                int   s1 = __shfl(idx_l, e1, 64);
                float w1 = __shfl(dv_l,  e1, 64);
                float4 v0 = reinterpret_cast<const float4*>(h + (size_t)s0 * D)[p];
                float4 v1 = reinterpret_cast<const float4*>(h + (size_t)s1 * D)[p];
                acc.x = fmaf(w0, v0.x, acc.x);
                acc.y = fmaf(w0, v0.y, acc.y);
                acc.z = fmaf(w0, v0.z, acc.z);
                acc.w = fmaf(w0, v0.w, acc.w);
                acc.x = fmaf(w1, v1.x, acc.x);
                acc.y = fmaf(w1, v1.y, acc.y);
                acc.z = fmaf(w1, v1.z, acc.z);
                acc.w = fmaf(w1, v1.w, acc.w);
            }
        }
        acc.x += __shfl_xor(acc.x, 16, 64);
        acc.y += __shfl_xor(acc.y, 16, 64);
        acc.z += __shfl_xor(acc.z, 16, 64);
        acc.w += __shfl_xor(acc.w, 16, 64);
        acc.x += __shfl_xor(acc.x, 32, 64);
        acc.y += __shfl_xor(acc.y, 32, 64);
        acc.z += __shfl_xor(acc.z, 32, 64);
        acc.w += __shfl_xor(acc.w, 32, 64);

        float y = 0.0f;
#pragma unroll
        for (int pp = 0; pp < 16; ++pp) {
            float sx = __shfl(acc.x, pp, 64);
            float sy = __shfl(acc.y, pp, 64);
            float sz = __shfl(acc.z, pp, 64);
            float sw = __shfl(acc.w, pp, 64);
            y = fmaf(sx, Wl[(4 * pp + 0) * D + lane], y);
            y = fmaf(sy, Wl[(4 * pp + 1) * D + lane], y);
            y = fmaf(sz, Wl[(4 * pp + 2) * D + lane], y);
            y = fmaf(sw, Wl[(4 * pp + 3) * D + lane], y);
        }
        float r;
        if (MODE == 0) r = fmaxf(dn * y, 0.0f);
        else           r = fmaf(dn, y, bv);
        out[(size_t)node * D + lane] = r;
    }
}

// ---- launch ----------------------------------------------------------------

extern "C" void kernel_launch(void* const* d_in, const int* in_sizes, int n_in,
                              void* d_out, int out_size, void* d_ws, size_t ws_size,
                              hipStream_t stream) {
    const float* x  = (const float*)d_in[0];
    const float* W1 = (const float*)d_in[1];
    const float* W2 = (const float*)d_in[2];
    const float* b2 = (const float*)d_in[3];
    const int*   ei = (const int*)d_in[4];

    int n  = in_sizes[0] / D;   // 100000
    int nE = in_sizes[4] / 2;   // 1600000
    const int* src = ei;        // message source
    const int* dst = ei + nE;   // aggregation target

    int B = (n + BKT_NODES - 1) >> BKT_SHIFT;  // 98 buckets (<=128 assumed)

    // workspace layout (aligned to 256B):
    //   row_ptr [n+1] | dinv [n] | bucket_cnt [128] | bucket_base [129] |
    //   bucket_cursor [128] | packed [nE] | adj [nE] | H [n*D]
    auto align = [](size_t v) { return (v + 255) & ~(size_t)255; };
    char* ws = (char*)d_ws;
    size_t off = 0;
    int* row_ptr   = (int*)(ws + off);   off += align((size_t)(n + 1) * 4);
    float* dinv    = (float*)(ws + off); off += align((size_t)n * 4);
    int* bucket_cnt    = (int*)(ws + off); off += align(128 * 4);
    int* bucket_base   = (int*)(ws + off); off += align(129 * 4);
    int* bucket_cursor = (int*)(ws + off); off += align(128 * 4);
    int* packed    = (int*)(ws + off);   off += align((size_t)nE * 4);
    int* adj       = (int*)(ws + off);   off += align((size_t)nE * 4);
    float* H       = (float*)(ws + off);
    float* out = (float*)d_out;

    int nchunks = (nE + CHUNK - 1) / CHUNK;  // 196

    // CSR build (binned, write-locality preserving)
    zero_int<<<1, 128, 0, stream>>>(bucket_cnt, 128);
    bucket_hist<<<nchunks, 256, 0, stream>>>(dst, bucket_cnt, nE);
    scan_buckets<<<1, 128, 0, stream>>>(bucket_cnt, bucket_base, bucket_cursor, row_ptr, B, n);
    partition<<<nchunks, 256, 0, stream>>>(src, dst, bucket_cursor, packed, nE, B);
    bucket_csr<<<B, BKT_NODES, 0, stream>>>(packed, bucket_base, row_ptr, dinv, adj, n);

    // layer 1 fused: H = relu(dinv * ((A_hat-gather of dinv*x) @ W1))
    agg_gemm<0><<<2048, 256, 0, stream>>>(x, row_ptr, adj, dinv, W1, nullptr, H, n);
    // layer 2 fused: out = dinv * (gather @ W2) + b2
    agg_gemm<1><<<2048, 256, 0, stream>>>(H, row_ptr, adj, dinv, W2, b2, out, n);
}

// Round 7
// 351.156 us; speedup vs baseline: 8.6792x; 1.0266x over previous
//
#include <hip/hip_runtime.h>

#define D 64
#define CHUNK 8192          // edges per partition block
#define BKT_SHIFT 10        // 1024 nodes per bucket
#define BKT_NODES 1024

// ---- misc ------------------------------------------------------------------

__global__ void zero_int(int* __restrict__ p, int n) {
    int i = blockIdx.x * blockDim.x + threadIdx.x;
    if (i < n) p[i] = 0;
}

// ---- level-1: bucket histogram of dst>>BKT_SHIFT ---------------------------

__global__ void bucket_hist(const int* __restrict__ dst, int* __restrict__ bucket_cnt,
                            int nE) {
    __shared__ int h[128];
    int t = threadIdx.x;
    if (t < 128) h[t] = 0;
    __syncthreads();
    int i0 = blockIdx.x * CHUNK;
    int cn = min(CHUNK, nE - i0);
    for (int i = t; i < cn; i += 256) atomicAdd(&h[dst[i0 + i] >> BKT_SHIFT], 1);
    __syncthreads();
    if (t < 128 && h[t] > 0) atomicAdd(&bucket_cnt[t], h[t]);
}

// ---- scan the <=128 bucket counts -> base & cursor; row_ptr[n] = nE --------

__global__ void scan_buckets(const int* __restrict__ bucket_cnt, int* __restrict__ bucket_base,
                             int* __restrict__ bucket_cursor, int* __restrict__ row_ptr,
                             int B, int n) {
    __shared__ int s[128];
    int t = threadIdx.x;  // 128 threads
    int v = (t < B) ? bucket_cnt[t] : 0;
    s[t] = v;
    __syncthreads();
    for (int off = 1; off < 128; off <<= 1) {
        int u = (t >= off) ? s[t - off] : 0;
        __syncthreads();
        s[t] += u;
        __syncthreads();
    }
    if (t < B) {
        int excl = s[t] - v;
        bucket_base[t] = excl;
        bucket_cursor[t] = excl;
    }
    if (t == 127) {
        bucket_base[B] = s[127];   // == nE
        row_ptr[n] = s[127];
    }
}

// ---- level-1 partition: chunk -> in-LDS counting sort -> contiguous runs ---
// Packed word: (dst & (BKT_NODES-1)) << 17 | src     (src < 2^17)

__global__ void partition(const int* __restrict__ src, const int* __restrict__ dst,
                          int* __restrict__ bucket_cursor, int* __restrict__ packed,
                          int nE, int B) {
    __shared__ int hist[128];            // counts, then local cursor
    __shared__ int delta[128];           // global_base - local_excl
    __shared__ int sorted[CHUNK];
    __shared__ unsigned char sortedb[CHUNK];
    int t = threadIdx.x;  // 256 threads
    int i0 = blockIdx.x * CHUNK;
    int cn = min(CHUNK, nE - i0);

    if (t < 128) hist[t] = 0;
    __syncthreads();
    for (int i = t; i < cn; i += 256) atomicAdd(&hist[dst[i0 + i] >> BKT_SHIFT], 1);
    __syncthreads();

    __shared__ int s[128];
    int v = (t < 128) ? hist[t] : 0;
    if (t < 128) s[t] = v;
    __syncthreads();
    for (int off = 1; off < 128; off <<= 1) {
        int u = (t >= off && t < 128) ? s[t - off] : 0;
        __syncthreads();
        if (t < 128) s[t] += u;
        __syncthreads();
    }
    if (t < 128) {
        int excl = s[t] - v;
        int rb = 0;
        if (t < B && v > 0) rb = atomicAdd(&bucket_cursor[t], v);
        delta[t] = rb - excl;
        hist[t] = excl;   // local cursor for the LDS scatter
    }
    __syncthreads();

    for (int i = t; i < cn; i += 256) {
        int d = dst[i0 + i];
        int b = d >> BKT_SHIFT;
        int pp = atomicAdd(&hist[b], 1);
        sorted[pp]  = ((d & (BKT_NODES - 1)) << 17) | src[i0 + i];
        sortedb[pp] = (unsigned char)b;
    }
    __syncthreads();

    for (int i = t; i < cn; i += 256) {
        packed[delta[sortedb[i]] + i] = sorted[i];
    }
}

// ---- level-2: per-bucket CSR finalize (count, scan, scatter in one window) -

__global__ void bucket_csr(const int* __restrict__ packed, const int* __restrict__ bucket_base,
                           int* __restrict__ row_ptr, float* __restrict__ dinv,
                           int* __restrict__ adj, int n) {
    __shared__ int s[BKT_NODES];
    __shared__ int cur[BKT_NODES];
    int t = threadIdx.x;  // 1024 threads
    int b = blockIdx.x;
    int lo = bucket_base[b], hi = bucket_base[b + 1];

    s[t] = 0;
    __syncthreads();
    for (int i = lo + t; i < hi; i += BKT_NODES) atomicAdd(&s[packed[i] >> 17], 1);
    __syncthreads();

    int v = s[t];
    __syncthreads();
    for (int off = 1; off < BKT_NODES; off <<= 1) {
        int u = (t >= off) ? s[t - off] : 0;
        __syncthreads();
        s[t] += u;
        __syncthreads();
    }
    int gbeg = lo + s[t] - v;   // exclusive prefix + bucket base
    int node = (b << BKT_SHIFT) + t;
    if (node < n) {
        row_ptr[node] = gbeg;
        dinv[node] = rsqrtf(1.0f + (float)v);   // self-loop included
    }
    cur[t] = gbeg;
    __syncthreads();

    for (int i = lo + t; i < hi; i += BKT_NODES) {
        int w = packed[i];
        int pos = atomicAdd(&cur[w >> 17], 1);
        adj[pos] = w & 0x1FFFF;
    }
}

// ---- fused layer: out = epi( dinv[i] * ((sum_{s in N(i)+i} dinv[s] h[s]) @ W) )
// One node per 16-lane quarter (4 consecutive nodes per wave). Lane p of a
// quarter holds features [4p..4p+3] as float4. Edge chunk of 16 per quarter is
// consumed in two groups of 8 back-to-back row loads -> 8 float4 gathers in
// flight per wave. Quarters with shorter lists issue zero-weight loads of
// row 0 (L1-hot). GEMM stays quarter-local (S broadcast via shfl within the
// quarter; W slices read from LDS, 4-way multicast across quarters).
// MODE 0: out = relu(dinv*S@W)        (layer 1, no bias)
// MODE 1: out = dinv*S@W + bias       (layer 2)
template <int MODE>
__launch_bounds__(256, 4)
__global__ void agg_gemm(const float* __restrict__ h, const int* __restrict__ row_ptr,
                         const int* __restrict__ adj, const float* __restrict__ dinv,
                         const float* __restrict__ W, const float* __restrict__ bias,
                         float* __restrict__ out, int n) {
    __shared__ float Wl[D * D];
    for (int i = threadIdx.x; i < D * D; i += blockDim.x) Wl[i] = W[i];
    __syncthreads();

    const int lane = threadIdx.x & 63;
    const int q = lane >> 4;   // quarter = which of the wave's 4 nodes
    const int p = lane & 15;   // feature group: features 4p..4p+3
    const int wave = (blockIdx.x * blockDim.x + threadIdx.x) >> 6;
    const int nw = (gridDim.x * blockDim.x) >> 6;

    const float4 bv = (MODE == 1) ? ((const float4*)bias)[p]
                                  : make_float4(0.f, 0.f, 0.f, 0.f);

    for (int nb = wave * 4; nb < n; nb += nw * 4) {
        int nq = nb + q;                 // this quarter's node
        bool valid = nq < n;
        int nqc = valid ? nq : 0;
        float dn = valid ? dinv[nqc] : 0.0f;
        int rb = row_ptr[nqc];
        int re = row_ptr[nqc + 1];
        int len = valid ? (re - rb) : 0;

        // self-loop term: full row held across the quarter's 16 lanes
        float4 sv = ((const float4*)(h + (size_t)nqc * D))[p];
        float4 acc;
        acc.x = dn * sv.x; acc.y = dn * sv.y; acc.z = dn * sv.z; acc.w = dn * sv.w;

        // max edge count across the wave's 4 quarters
        int lm = len;
        lm = max(lm, __shfl_xor(lm, 16, 64));
        lm = max(lm, __shfl_xor(lm, 32, 64));

        for (int base = 0; base < lm; base += 16) {
            int rem = len - base;        // may be <= 0 for short quarters
            int idx_l = 0; float w_l = 0.0f;
            if (p < rem) {
                idx_l = adj[rb + base + p];
                w_l = dinv[idx_l];
            }
#pragma unroll
            for (int jj = 0; jj < 16; jj += 8) {
                int ss[8]; float ww[8]; float4 vv[8];
#pragma unroll
                for (int u = 0; u < 8; ++u) {
                    int e = (q << 4) | (jj + u);
                    ss[u] = __shfl(idx_l, e, 64);
                    ww[u] = __shfl(w_l, e, 64);
                }
#pragma unroll
                for (int u = 0; u < 8; ++u) {
                    vv[u] = ((const float4*)(h + (size_t)ss[u] * D))[p];
                }
#pragma unroll
                for (int u = 0; u < 8; ++u) {
                    acc.x = fmaf(ww[u], vv[u].x, acc.x);
                    acc.y = fmaf(ww[u], vv[u].y, acc.y);
                    acc.z = fmaf(ww[u], vv[u].z, acc.z);
                    acc.w = fmaf(ww[u], vv[u].w, acc.w);
                }
            }
        }

        // quarter-local GEMM: y[4p+c] = sum_k S[k] * W[k][4p+c]
        float4 y = make_float4(0.f, 0.f, 0.f, 0.f);
#pragma unroll
        for (int kp = 0; kp < 16; ++kp) {
            int sl = (q << 4) | kp;
            float s0 = __shfl(acc.x, sl, 64);   // S[4kp+0]
            float s1 = __shfl(acc.y, sl, 64);   // S[4kp+1]
            float s2 = __shfl(acc.z, sl, 64);   // S[4kp+2]
            float s3 = __shfl(acc.w, sl, 64);   // S[4kp+3]
            const float4 w0 = *(const float4*)&Wl[(4 * kp + 0) * D + 4 * p];
            const float4 w1 = *(const float4*)&Wl[(4 * kp + 1) * D + 4 * p];
            const float4 w2 = *(const float4*)&Wl[(4 * kp + 2) * D + 4 * p];
            const float4 w3 = *(const float4*)&Wl[(4 * kp + 3) * D + 4 * p];
            y.x = fmaf(s0, w0.x, fmaf(s1, w1.x, fmaf(s2, w2.x, fmaf(s3, w3.x, y.x))));
            y.y = fmaf(s0, w0.y, fmaf(s1, w1.y, fmaf(s2, w2.y, fmaf(s3, w3.y, y.y))));
            y.z = fmaf(s0, w0.z, fmaf(s1, w1.z, fmaf(s2, w2.z, fmaf(s3, w3.z, y.z))));
            y.w = fmaf(s0, w0.w, fmaf(s1, w1.w, fmaf(s2, w2.w, fmaf(s3, w3.w, y.w))));
        }

        float4 r;
        if (MODE == 0) {
            r.x = fmaxf(dn * y.x, 0.f);
            r.y = fmaxf(dn * y.y, 0.f);
            r.z = fmaxf(dn * y.z, 0.f);
            r.w = fmaxf(dn * y.w, 0.f);
        } else {
            r.x = fmaf(dn, y.x, bv.x);
            r.y = fmaf(dn, y.y, bv.y);
            r.z = fmaf(dn, y.z, bv.z);
            r.w = fmaf(dn, y.w, bv.w);
        }
        if (valid) ((float4*)(out + (size_t)nq * D))[p] = r;
    }
}

// ---- launch ----------------------------------------------------------------

extern "C" void kernel_launch(void* const* d_in, const int* in_sizes, int n_in,
                              void* d_out, int out_size, void* d_ws, size_t ws_size,
                              hipStream_t stream) {
    const float* x  = (const float*)d_in[0];
    const float* W1 = (const float*)d_in[1];
    const float* W2 = (const float*)d_in[2];
    const float* b2 = (const float*)d_in[3];
    const int*   ei = (const int*)d_in[4];

    int n  = in_sizes[0] / D;   // 100000
    int nE = in_sizes[4] / 2;   // 1600000
    const int* src = ei;        // message source
    const int* dst = ei + nE;   // aggregation target

    int B = (n + BKT_NODES - 1) >> BKT_SHIFT;  // 98 buckets (<=128 assumed)

    // workspace layout (aligned to 256B):
    //   row_ptr [n+1] | dinv [n] | bucket_cnt [128] | bucket_base [129] |
    //   bucket_cursor [128] | packed [nE] | adj [nE] | H [n*D]
    auto align = [](size_t v) { return (v + 255) & ~(size_t)255; };
    char* ws = (char*)d_ws;
    size_t off = 0;
    int* row_ptr   = (int*)(ws + off);   off += align((size_t)(n + 1) * 4);
    float* dinv    = (float*)(ws + off); off += align((size_t)n * 4);
    int* bucket_cnt    = (int*)(ws + off); off += align(128 * 4);
    int* bucket_base   = (int*)(ws + off); off += align(129 * 4);
    int* bucket_cursor = (int*)(ws + off); off += align(128 * 4);
    int* packed    = (int*)(ws + off);   off += align((size_t)nE * 4);
    int* adj       = (int*)(ws + off);   off += align((size_t)nE * 4);
    float* H       = (float*)(ws + off);
    float* out = (float*)d_out;

    int nchunks = (nE + CHUNK - 1) / CHUNK;  // 196

    // CSR build (binned, write-locality preserving)
    zero_int<<<1, 128, 0, stream>>>(bucket_cnt, 128);
    bucket_hist<<<nchunks, 256, 0, stream>>>(dst, bucket_cnt, nE);
    scan_buckets<<<1, 128, 0, stream>>>(bucket_cnt, bucket_base, bucket_cursor, row_ptr, B, n);
    partition<<<nchunks, 256, 0, stream>>>(src, dst, bucket_cursor, packed, nE, B);
    bucket_csr<<<B, BKT_NODES, 0, stream>>>(packed, bucket_base, row_ptr, dinv, adj, n);

    // layer 1 fused: H = relu(dinv * ((A_hat-gather of dinv*x) @ W1))
    agg_gemm<0><<<2048, 256, 0, stream>>>(x, row_ptr, adj, dinv, W1, nullptr, H, n);
    // layer 2 fused: out = dinv * (gather @ W2) + b2
    agg_gemm<1><<<2048, 256, 0, stream>>>(H, row_ptr, adj, dinv, W2, b2, out, n);
}